// Round 18
// baseline (470.407 us; speedup 1.0000x reference)
//
#include <hip/hip_runtime.h>
#include <hip/hip_bf16.h>

// Problem constants (from reference)
#define S 2048
#define W 96
#define E 100
#define H 100
#define PD 50

typedef float f32x4 __attribute__((ext_vector_type(4)));

__device__ __forceinline__ float fast_rcp(float x) { return __builtin_amdgcn_rcpf(x); }

// One DPP reduction stage: x += dpp_move(x). Builtin form (hazards handled).
template<int CTRL, int RM, bool BND>
__device__ __forceinline__ float dpp_add(float x) {
    int t = __builtin_amdgcn_update_dpp(0, __float_as_int(x), CTRL, RM, 0xf, BND);
    return x + __int_as_float(t);
}

// Full-wave (64-lane) sum; returns total as a wave-uniform value.
__device__ __forceinline__ float wave_sum_bcast(float x) {
    x = dpp_add<0x111, 0xf, true >(x);  // row_shr:1
    x = dpp_add<0x112, 0xf, true >(x);  // row_shr:2
    x = dpp_add<0x114, 0xf, true >(x);  // row_shr:4
    x = dpp_add<0x118, 0xf, true >(x);  // row_shr:8
    x = dpp_add<0x142, 0xa, false>(x);  // row_bcast:15
    x = dpp_add<0x143, 0xc, false>(x);  // row_bcast:31
    return __int_as_float(__builtin_amdgcn_readlane(__float_as_int(x), 63));
}

// K1: ragged-prefix mean pool over word embeddings + doc_feat accumulation
__global__ __launch_bounds__(128) void k_sent(const int* __restrict__ x,
                                              const float* __restrict__ word_emb,
                                              float* __restrict__ sent,
                                              float* __restrict__ doc_sum) {
    __shared__ int toks[W];
    __shared__ int s_len;
    const int i = blockIdx.x, t = threadIdx.x;
    if (t == 0) s_len = 0;
    __syncthreads();
    if (t < W) {
        int tok = x[i * W + t];
        toks[t] = tok;
        if (tok > 0) atomicAdd(&s_len, 1);
    }
    __syncthreads();
    const int len = s_len;
    if (t < E) {
        float acc = 0.0f;
        for (int j = 0; j < len; ++j)
            acc += word_emb[toks[j] * E + t];   // coalesced across t
        float val = acc / (float)max(len, 1);
        sent[i * E + t] = val;
        atomicAdd(&doc_sum[t], val * (1.0f / (float)S));
    }
}

// K2: doc = tanh(doc_feat @ fc1_w.T + fc1_b); cvec = Wc + Ws @ doc
__global__ __launch_bounds__(128) void k_doc(const float* __restrict__ doc_sum,
                                             const float* __restrict__ fc1_w,
                                             const float* __restrict__ fc1_b,
                                             const float* __restrict__ Wc,
                                             const float* __restrict__ Ws,
                                             float* __restrict__ cvec) {
    __shared__ float s_df[E];
    __shared__ float s_doc[H];
    const int t = threadIdx.x;
    if (t < E) s_df[t] = doc_sum[t];
    __syncthreads();
    if (t < H) {
        float acc = fc1_b[t];
        for (int k = 0; k < E; ++k) acc += s_df[k] * fc1_w[t * E + k];
        s_doc[t] = tanhf(acc);
    }
    __syncthreads();
    if (t < H) {
        float c = Wc[t];
        for (int j = 0; j < H; ++j) c += Ws[t * H + j] * s_doc[j];
        cvec[t] = c;
    }
}

// K3: per-row padded layout for the scan (unchanged from R13/R17).
__global__ __launch_bounds__(128) void k_row(const float* __restrict__ sent,
                                             const float* __restrict__ fc2_w,
                                             const float* __restrict__ fc2_b,
                                             const float* __restrict__ Wr,
                                             const float* __restrict__ cvec,
                                             const float* __restrict__ pos_emb,
                                             const float* __restrict__ Wp,
                                             const float* __restrict__ bptr,
                                             float* __restrict__ packed) {
    __shared__ float s_sent[E];
    __shared__ float s_h[H];
    __shared__ float red[128];
    const int i = blockIdx.x, t = threadIdx.x;
    float* row = packed + (size_t)i * 256;
    if (t < E) s_sent[t] = sent[i * E + t];
    __syncthreads();
    float hv = 0.0f;
    if (t < H) {
        float acc = fc2_b[t];
        for (int k = 0; k < E; ++k) acc += s_sent[k] * fc2_w[t * E + k];
        hv = tanhf(acc);
        s_h[t] = hv;
    }
    __syncthreads();
    {
        const int m = t >> 1, o = (t & 1) * 2;
        if (t < H) {
            float acc = 0.0f;
            for (int k = 0; k < H; ++k) acc += s_h[k] * Wr[k * H + t];   // coalesced across t
            row[m * 4 + o]     = 1.44269504f * acc;  // L2E * hWr
            row[m * 4 + o + 1] = hv;                 // h
        } else {
            if (t != 100) row[m * 4 + o] = 0.0f;   // dead w (element 200 reserved for q)
            row[m * 4 + o + 1] = 0.0f;             // dead h
        }
    }
    float p = 0.0f;
    if (t < H) p = hv * cvec[t];
    if (t < PD) p += pos_emb[i * PD + t] * Wp[t];
    red[t] = p;
    __syncthreads();
    for (int m = 64; m > 0; m >>= 1) {
        if (t < m) red[t] += red[t + m];
        __syncthreads();
    }
    if (t == 0) row[200] = -1.44269504f * (red[0] + bptr[0]);  // slot 50 .x
}

// K4: 2-step-lookahead scan. State t = tanh(s) kept EXACT via Moebius+cubic
// (off-chain). Logit reconstructed from 2-step-lagged state:
//   total_J = A_J + p_{J-2}*B_J + p_{J-1}*C_J
//   A_J = sum w_J*t^(J-2);  B_J = sum w_J*g_{J-2};  C_J = sum w_J*g_{J-1}
//   g_m = h_m*(1 - t^2)  (Jacobian of tanh-sum), all trees built 2 steps
// ahead, OFF the serial chain. Chain per step: fmaf -> exp2 -> add -> rcp.
// q rides in A via lane50 t0 == 1 (exact, never polluted: its h = 0).
// Error: one-shot O((h*p)^2) per logit (~1e-4), state exact -> no compounding.
__global__ __launch_bounds__(64, 1) void k_scan(const f32x4* __restrict__ packed,
                                                float* __restrict__ out) {
    const int l = threadIdx.x;
    const f32x4* pf = packed + l;

    float t0 = (l == 50) ? 1.0f : 0.0f;   // t state; lane50 carries q via t0=1
    float t1 = 0.0f, probbuf = 1.0f;
    float p1 = 0.0f, p2 = 0.0f;           // p_{J-1}, p_{J-2}
    float hp0 = 0.0f, hp1 = 0.0f;         // h_{J-1} (carried across reissues)
    float aE, bE, cE, aO, bO, cO;         // A/B/C pipelines (even/odd steps)

    f32x4 a0, a1, a2, a3, a4, a5, a6, a7;
    f32x4 b0, b1, b2, b3, b4, b5, b6, b7;

#define SB() __builtin_amdgcn_sched_barrier(0)
#define ISSUE(AR, PTR) \
    asm volatile("global_load_dwordx4 %0, %1, off" : "=v"(AR) : "v"(PTR))
#define ISSUE8(R0, R1, R2, R3, R4, R5, R6, R7)                                \
    SB();                                                                     \
    ISSUE(R0, pf + 0 * 64); ISSUE(R1, pf + 1 * 64);                           \
    ISSUE(R2, pf + 2 * 64); ISSUE(R3, pf + 3 * 64);                           \
    ISSUE(R4, pf + 4 * 64); ISSUE(R5, pf + 5 * 64);                           \
    ISSUE(R6, pf + 6 * 64); ISSUE(R7, pf + 7 * 64);                           \
    pf += 8 * 64;                                                             \
    SB();
#define WAIT_ALL()                                                            \
    SB();                                                                     \
    asm volatile("s_waitcnt vmcnt(0)" ::: "memory");                          \
    SB();

// CUR = row J (h for B-tree), NXT = row J+1 (h for C-tree),
// WP2 = row J+2 (w for all trees). AX/BX/CX = this parity's pipeline regs.
#define STEP(CUR, NXT, WP2, AX, BX, CX, IDX, G)                               \
    {                                                                         \
        /* serial chain: tot -> exp2 -> av -> p */                            \
        float tot = fmaf(p1, CX, fmaf(p2, BX, AX));                           \
        float e2 = exp2f(tot);                                                \
        float av = e2 + 1.0f;                                                 \
        float pj = fast_rcp(av);                                              \
        /* off-chain: exact Moebius state update with h_{J-1}, p_{J-1} */     \
        float d0 = hp0 * p1, d1 = hp1 * p1;                                   \
        float u0 = d0 * d0, u1 = d1 * d1;                                     \
        float T0 = d0 * fmaf(u0, -0.33333334f, 1.0f);                         \
        float T1 = d1 * fmaf(u1, -0.33333334f, 1.0f);                         \
        float dM0 = fmaf(t0, T0, 1.0f), dM1 = fmaf(t1, T1, 1.0f);             \
        t0 = (t0 + T0) * fast_rcp(dM0);                                       \
        t1 = (t1 + T1) * fast_rcp(dM1);                                       \
        /* off-chain: trees for step J+2 (2 periods of slack) */              \
        float om0 = fmaf(-t0, t0, 1.0f), om1 = fmaf(-t1, t1, 1.0f);           \
        float gB0 = CUR.y * om0, gB1 = CUR.w * om1;                           \
        float gC0 = NXT.y * om0, gC1 = NXT.w * om1;                           \
        float pA = fmaf(t0, WP2.x, t1 * WP2.z);                               \
        float pB = fmaf(gB0, WP2.x, gB1 * WP2.z);                             \
        float pC = fmaf(gC0, WP2.x, gC1 * WP2.z);                             \
        AX = wave_sum_bcast(pA);                                              \
        BX = wave_sum_bcast(pB);                                              \
        CX = wave_sum_bcast(pC);                                              \
        hp0 = CUR.y; hp1 = CUR.w;                                             \
        p2 = p1; p1 = pj;                                                     \
        probbuf = (l == ((G + IDX) & 63)) ? av : probbuf;                     \
    }
#define MIDWAIT()                                                             \
    SB();                                                                     \
    asm volatile("s_waitcnt vmcnt(0)" ::: "memory");                          \
    SB();
// Q0, Q1 = first two regs of the OTHER batch (rows G+8, G+9) for slots 6-7.
#define COMPUTE8(R0, R1, R2, R3, R4, R5, R6, R7, Q0, Q1, G)                   \
    STEP(R0, R1, R2, aE, bE, cE, 0, G)                                        \
    STEP(R1, R2, R3, aO, bO, cO, 1, G)                                        \
    STEP(R2, R3, R4, aE, bE, cE, 2, G)                                        \
    STEP(R3, R4, R5, aO, bO, cO, 3, G)                                        \
    STEP(R4, R5, R6, aE, bE, cE, 4, G)                                        \
    STEP(R5, R6, R7, aO, bO, cO, 5, G)                                        \
    MIDWAIT()                                                                 \
    STEP(R6, R7, Q0, aE, bE, cE, 6, G)                                        \
    STEP(R7, Q0, Q1, aO, bO, cO, 7, G)                                        \
    if (((G) & 63) == 56) out[((G) & ~63) + l] = fast_rcp(probbuf);

    // Preload batch 0 and land it.
    ISSUE8(a0, a1, a2, a3, a4, a5, a6, a7)
    WAIT_ALL()

    // Prologue trees: A_0; A_1 and C_1 (B's are x p_{-1}=p_{-2}=0).
    {
        float pA0 = fmaf(t0, a0.x, t1 * a0.z);
        aE = wave_sum_bcast(pA0);  bE = 0.0f;  cE = 0.0f;
        float pA1 = fmaf(t0, a1.x, t1 * a1.z);
        aO = wave_sum_bcast(pA1);  bO = 0.0f;
        float om0 = fmaf(-t0, t0, 1.0f), om1 = fmaf(-t1, t1, 1.0f);
        float g0 = a0.y * om0, g1 = a0.w * om1;
        float pC1 = fmaf(g0, a1.x, g1 * a1.z);
        cO = wave_sum_bcast(pC1);
    }

    for (int base = 0; base < S; base += 16) {
        ISSUE8(b0, b1, b2, b3, b4, b5, b6, b7)            // rows base+8..+15
        COMPUTE8(a0, a1, a2, a3, a4, a5, a6, a7, b0, b1, base)
        WAIT_ALL()
        ISSUE8(a0, a1, a2, a3, a4, a5, a6, a7)            // rows base+16..+23
        COMPUTE8(b0, b1, b2, b3, b4, b5, b6, b7, a0, a1, base + 8)
        WAIT_ALL()
    }
#undef COMPUTE8
#undef MIDWAIT
#undef STEP
#undef WAIT_ALL
#undef ISSUE8
#undef ISSUE
#undef SB
}

extern "C" void kernel_launch(void* const* d_in, const int* in_sizes, int n_in,
                              void* d_out, int out_size, void* d_ws, size_t ws_size,
                              hipStream_t stream) {
    const int*   x        = (const int*)  d_in[0];
    const float* word_emb = (const float*)d_in[1];
    const float* pos_emb  = (const float*)d_in[2];
    const float* fc1_w    = (const float*)d_in[3];
    const float* fc1_b    = (const float*)d_in[4];
    const float* fc2_w    = (const float*)d_in[5];
    const float* fc2_b    = (const float*)d_in[6];
    const float* Wc       = (const float*)d_in[7];
    const float* Ws       = (const float*)d_in[8];
    const float* Wr       = (const float*)d_in[9];
    const float* Wp       = (const float*)d_in[10];
    const float* bptr     = (const float*)d_in[11];
    float* out = (float*)d_out;

    float* wsf      = (float*)d_ws;
    float* doc_sum  = wsf;                 // 128 (zeroed each call)
    float* cvec     = wsf + 128;           // 128
    float* sent     = wsf + 256;           // S*E = 204800
    float* packed   = sent + S * E;        // (S+16)*256 floats, 16B-aligned offset

    hipMemsetAsync(doc_sum, 0, E * sizeof(float), stream);
    hipMemsetAsync(packed + (size_t)S * 256, 0, 16 * 256 * sizeof(float), stream);
    k_sent<<<S, 128, 0, stream>>>(x, word_emb, sent, doc_sum);
    k_doc<<<1, 128, 0, stream>>>(doc_sum, fc1_w, fc1_b, Wc, Ws, cvec);
    k_row<<<S, 128, 0, stream>>>(sent, fc2_w, fc2_b, Wr, cvec, pos_emb, Wp, bptr, packed);
    k_scan<<<1, 64, 0, stream>>>((const f32x4*)packed, out);
}

// Round 19
// 363.701 us; speedup vs baseline: 1.2934x; 1.2934x over previous
//
#include <hip/hip_runtime.h>
#include <hip/hip_bf16.h>

// Problem constants (from reference)
#define S 2048
#define W 96
#define E 100
#define H 100
#define PD 50

typedef float f32x4 __attribute__((ext_vector_type(4)));

__device__ __forceinline__ float fast_rcp(float x) { return __builtin_amdgcn_rcpf(x); }

// One DPP reduction stage: x += dpp_move(x). Builtin form: the compiler's
// hazard recognizer handles DPP wait-states (R14/R15: raw asm DPP needs
// manual s_nops and ends up slower).
template<int CTRL, int RM, bool BND>
__device__ __forceinline__ float dpp_add(float x) {
    int t = __builtin_amdgcn_update_dpp(0, __float_as_int(x), CTRL, RM, 0xf, BND);
    return x + __int_as_float(t);
}

// Full-wave (64-lane) sum; returns total as a wave-uniform value.
__device__ __forceinline__ float wave_sum_bcast(float x) {
    x = dpp_add<0x111, 0xf, true >(x);  // row_shr:1
    x = dpp_add<0x112, 0xf, true >(x);  // row_shr:2
    x = dpp_add<0x114, 0xf, true >(x);  // row_shr:4
    x = dpp_add<0x118, 0xf, true >(x);  // row_shr:8
    x = dpp_add<0x142, 0xa, false>(x);  // row_bcast:15
    x = dpp_add<0x143, 0xc, false>(x);  // row_bcast:31
    return __int_as_float(__builtin_amdgcn_readlane(__float_as_int(x), 63));
}

// K1: ragged-prefix mean pool, vectorized: 64 threads, float2 loads (rows are
// 8B-aligned: tok*400B), 4 independent accumulators for load-level parallelism.
__global__ __launch_bounds__(64) void k_sent(const int* __restrict__ x,
                                             const float* __restrict__ word_emb,
                                             float* __restrict__ sent,
                                             float* __restrict__ doc_sum) {
    __shared__ int toks[W];
    __shared__ int s_len;
    const int i = blockIdx.x, t = threadIdx.x;
    if (t == 0) s_len = 0;
    __syncthreads();
    for (int j = t; j < W; j += 64) {
        int tok = x[i * W + j];
        toks[j] = tok;
        if (tok > 0) atomicAdd(&s_len, 1);
    }
    __syncthreads();
    const int len = s_len;
    if (t < E / 2) {                       // 50 threads, one float2 column each
        const float2* we = (const float2*)word_emb;
        float2 A = make_float2(0.f, 0.f), B = make_float2(0.f, 0.f);
        float2 C = make_float2(0.f, 0.f), Dv = make_float2(0.f, 0.f);
        int j = 0;
        for (; j + 3 < len; j += 4) {      // 4 independent load streams
            float2 v0 = we[toks[j]     * 50 + t];
            float2 v1 = we[toks[j + 1] * 50 + t];
            float2 v2 = we[toks[j + 2] * 50 + t];
            float2 v3 = we[toks[j + 3] * 50 + t];
            A.x += v0.x; A.y += v0.y;  B.x += v1.x; B.y += v1.y;
            C.x += v2.x; C.y += v2.y;  Dv.x += v3.x; Dv.y += v3.y;
        }
        for (; j < len; ++j) {
            float2 v = we[toks[j] * 50 + t];
            A.x += v.x; A.y += v.y;
        }
        const float dlen = (float)max(len, 1);
        float vx = ((A.x + B.x) + (C.x + Dv.x)) / dlen;
        float vy = ((A.y + B.y) + (C.y + Dv.y)) / dlen;
        ((float2*)sent)[i * 50 + t] = make_float2(vx, vy);
        atomicAdd(&doc_sum[2 * t],     vx * (1.0f / (float)S));
        atomicAdd(&doc_sum[2 * t + 1], vy * (1.0f / (float)S));
    }
}

// K2: doc = tanh(doc_feat @ fc1_w.T + fc1_b); cvec = Wc + Ws @ doc
__global__ __launch_bounds__(128) void k_doc(const float* __restrict__ doc_sum,
                                             const float* __restrict__ fc1_w,
                                             const float* __restrict__ fc1_b,
                                             const float* __restrict__ Wc,
                                             const float* __restrict__ Ws,
                                             float* __restrict__ cvec) {
    __shared__ float s_df[E];
    __shared__ float s_doc[H];
    const int t = threadIdx.x;
    if (t < E) s_df[t] = doc_sum[t];
    __syncthreads();
    if (t < H) {
        float acc = fc1_b[t];
        for (int k = 0; k < E; ++k) acc += s_df[k] * fc1_w[t * E + k];
        s_doc[t] = tanhf(acc);
    }
    __syncthreads();
    if (t < H) {
        float c = Wc[t];
        for (int j = 0; j < H; ++j) c += Ws[t * H + j] * s_doc[j];
        cvec[t] = c;
    }
}

// K3: per-row padded layout for the scan (R12/R13 layout).
// packed row i = 64 float4 slots; slot m = (L2E*hWr[2m], h[2m], L2E*hWr[2m+1], h[2m+1]),
// zeros for k>=100.  Slot 50 .x (element 200, a DEAD hWr position) carries
// q[i] = -L2E*(h.cvec + pos.Wp + b); the scan keeps lane 50's t0 = 1 so
// part(lane50) = t0*q injects q into the wave sum for free.
// Grid is S+16: pad blocks (i >= S) zero-fill their row for the scan's
// prefetch overrun (replaces the separate memset launch).
__global__ __launch_bounds__(128) void k_row(const float* __restrict__ sent,
                                             const float* __restrict__ fc2_w,
                                             const float* __restrict__ fc2_b,
                                             const float* __restrict__ Wr,
                                             const float* __restrict__ cvec,
                                             const float* __restrict__ pos_emb,
                                             const float* __restrict__ Wp,
                                             const float* __restrict__ bptr,
                                             float* __restrict__ packed) {
    __shared__ float s_sent[E];
    __shared__ float s_h[H];
    __shared__ float red[128];
    const int i = blockIdx.x, t = threadIdx.x;
    float* row = packed + (size_t)i * 256;
    if (i >= S) {                       // zero-fill pad rows
        row[2 * t] = 0.0f;
        row[2 * t + 1] = 0.0f;
        return;
    }
    if (t < E) s_sent[t] = sent[i * E + t];
    __syncthreads();
    float hv = 0.0f;
    if (t < H) {
        float acc = fc2_b[t];
        for (int k = 0; k < E; ++k) acc += s_sent[k] * fc2_w[t * E + k];
        hv = tanhf(acc);
        s_h[t] = hv;
    }
    __syncthreads();
    {
        const int m = t >> 1, o = (t & 1) * 2;
        if (t < H) {
            float acc = 0.0f;
            for (int k = 0; k < H; ++k) acc += s_h[k] * Wr[k * H + t];   // coalesced across t
            row[m * 4 + o]     = 1.44269504f * acc;  // L2E * hWr
            row[m * 4 + o + 1] = hv;                 // h
        } else {
            if (t != 100) row[m * 4 + o] = 0.0f;   // dead w (element 200 reserved for q)
            row[m * 4 + o + 1] = 0.0f;             // dead h
        }
    }
    float p = 0.0f;
    if (t < H) p = hv * cvec[t];
    if (t < PD) p += pos_emb[i * PD + t] * Wp[t];
    red[t] = p;
    __syncthreads();
    for (int m = 64; m > 0; m >>= 1) {
        if (t < m) red[t] += red[t + m];
        __syncthreads();
    }
    if (t == 0) row[200] = -1.44269504f * (red[0] + bptr[0]);  // slot 50 .x
}

// K4: sequential scan — EXACT revert to the R12-submitted kernel (best
// measured: 240us). Batch-8 double-buffered manual pipeline, pinned schedule,
// ONE rcp on the recurrence chain:
//   a = 1 + 2^total  (prob = 1/a off-chain, output only)
//   tanh-addition scaled by a^3: inner = h*a^2 - h^3/3 (h^3/3 off-chain)
//   N = t*a^3 + inner;  D = a^3 + t*inner;  t' = N * rcp(D)
// Lane 50: t0 = 1 forever (its h = 0), injecting q = row[200] for free.
// Structural ledger (R10/R14/R15/R16/R18): every deviation from this
// structure regressed; only algebra-depth cuts (R12, R13) won.
__global__ __launch_bounds__(64, 1) void k_scan(const f32x4* __restrict__ packed,
                                                float* __restrict__ out) {
    const int l = threadIdx.x;
    const f32x4* pf = packed + l;

    float t0 = (l == 50) ? 1.0f : 0.0f;   // t = tanh(s); lane50 carries q
    float t1 = 0.0f, probbuf = 0.0f;

    f32x4 x0, x1, x2, x3, x4, x5, x6, x7;
    f32x4 y0, y1, y2, y3, y4, y5, y6, y7;

#define SB() __builtin_amdgcn_sched_barrier(0)
#define ISSUE(AR, PTR) \
    asm volatile("global_load_dwordx4 %0, %1, off" : "=v"(AR) : "v"(PTR))
#define ISSUE8(P0, P1, P2, P3, P4, P5, P6, P7)                                \
    SB();                                                                     \
    ISSUE(P0, pf + 0 * 64); ISSUE(P1, pf + 1 * 64);                           \
    ISSUE(P2, pf + 2 * 64); ISSUE(P3, pf + 3 * 64);                           \
    ISSUE(P4, pf + 4 * 64); ISSUE(P5, pf + 5 * 64);                           \
    ISSUE(P6, pf + 6 * 64); ISSUE(P7, pf + 7 * 64);                           \
    pf += 8 * 64;                                                             \
    SB();
#define WAIT_ALL()                                                            \
    SB();                                                                     \
    asm volatile("s_waitcnt vmcnt(0)" ::: "memory");                          \
    SB();

#define STEP(CA_, IDX, G)                                                     \
    {                                                                         \
        /* off-chain: h^3/3 (from loaded data, lands a full batch early) */   \
        float h30 = CA_.y * CA_.y * CA_.y * 0.33333334f;                      \
        float h31 = CA_.w * CA_.w * CA_.w * 0.33333334f;                      \
        float part = fmaf(t0, CA_.x, t1 * CA_.z);                             \
        float total = wave_sum_bcast(part);  /* = L2E*(hWr.tanh(s) - pre) */  \
        float e2 = exp2f(total);                                              \
        float a  = e2 + 1.0f;                                                 \
        float a2 = a * a;                                                     \
        float a3 = a2 * a;                                                    \
        float in0 = fmaf(CA_.y, a2, -h30);                                    \
        float in1 = fmaf(CA_.w, a2, -h31);                                    \
        float N0 = fmaf(t0, a3, in0), D0 = fmaf(t0, in0, a3);                 \
        float N1 = fmaf(t1, a3, in1), D1 = fmaf(t1, in1, a3);                 \
        t0 = N0 * fast_rcp(D0);                                               \
        t1 = N1 * fast_rcp(D1);                                               \
        float prob = fast_rcp(a);            /* off the recurrence chain */   \
        probbuf = (l == ((G + IDX) & 63)) ? prob : probbuf;                   \
    }
#define COMPUTE8(P0, P1, P2, P3, P4, P5, P6, P7, G)                           \
    STEP(P0, 0, G) STEP(P1, 1, G) STEP(P2, 2, G) STEP(P3, 3, G)               \
    STEP(P4, 4, G) STEP(P5, 5, G) STEP(P6, 6, G) STEP(P7, 7, G)               \
    if (((G) & 63) == 56) out[((G) & ~63) + l] = probbuf;

    // Preload batch 0 into X and land it.
    ISSUE8(x0, x1, x2, x3, x4, x5, x6, x7)
    WAIT_ALL()

    for (int base = 0; base < S; base += 16) {
        ISSUE8(y0, y1, y2, y3, y4, y5, y6, y7)            // rows base+8..base+15
        COMPUTE8(x0, x1, x2, x3, x4, x5, x6, x7, base)    // rows base..base+7
        WAIT_ALL()                                        // Y landed (issued ~1500cy ago)
        ISSUE8(x0, x1, x2, x3, x4, x5, x6, x7)            // rows base+16..base+23
        COMPUTE8(y0, y1, y2, y3, y4, y5, y6, y7, base + 8)
        WAIT_ALL()                                        // X landed
    }
#undef COMPUTE8
#undef STEP
#undef WAIT_ALL
#undef ISSUE8
#undef ISSUE
#undef SB
}

extern "C" void kernel_launch(void* const* d_in, const int* in_sizes, int n_in,
                              void* d_out, int out_size, void* d_ws, size_t ws_size,
                              hipStream_t stream) {
    const int*   x        = (const int*)  d_in[0];
    const float* word_emb = (const float*)d_in[1];
    const float* pos_emb  = (const float*)d_in[2];
    const float* fc1_w    = (const float*)d_in[3];
    const float* fc1_b    = (const float*)d_in[4];
    const float* fc2_w    = (const float*)d_in[5];
    const float* fc2_b    = (const float*)d_in[6];
    const float* Wc       = (const float*)d_in[7];
    const float* Ws       = (const float*)d_in[8];
    const float* Wr       = (const float*)d_in[9];
    const float* Wp       = (const float*)d_in[10];
    const float* bptr     = (const float*)d_in[11];
    float* out = (float*)d_out;

    float* wsf      = (float*)d_ws;
    float* doc_sum  = wsf;                 // 128 (zeroed each call)
    float* cvec     = wsf + 128;           // 128
    float* sent     = wsf + 256;           // S*E = 204800
    float* packed   = sent + S * E;        // (S+16)*256 floats, 16B-aligned offset

    hipMemsetAsync(doc_sum, 0, E * sizeof(float), stream);
    k_sent<<<S, 64, 0, stream>>>(x, word_emb, sent, doc_sum);
    k_doc<<<1, 128, 0, stream>>>(doc_sum, fc1_w, fc1_b, Wc, Ws, cvec);
    k_row<<<S + 16, 128, 0, stream>>>(sent, fc2_w, fc2_b, Wr, cvec, pos_emb, Wp, bptr, packed);
    k_scan<<<1, 64, 0, stream>>>((const f32x4*)packed, out);
}

// Round 20
// 314.957 us; speedup vs baseline: 1.4936x; 1.1548x over previous
//
#include <hip/hip_runtime.h>
#include <hip/hip_bf16.h>

// Problem constants (from reference)
#define S 2048
#define W 96
#define E 100
#define H 100
#define PD 50

typedef float f32x4 __attribute__((ext_vector_type(4)));

__device__ __forceinline__ float fast_rcp(float x) { return __builtin_amdgcn_rcpf(x); }

// One DPP reduction stage: x += dpp_move(x). Builtin form: the compiler's
// hazard recognizer handles DPP wait-states (R14/R15: raw asm DPP needs
// manual s_nops and ends up slower).
template<int CTRL, int RM, bool BND>
__device__ __forceinline__ float dpp_add(float x) {
    int t = __builtin_amdgcn_update_dpp(0, __float_as_int(x), CTRL, RM, 0xf, BND);
    return x + __int_as_float(t);
}

// Full-wave (64-lane) sum; returns total as a wave-uniform value.
__device__ __forceinline__ float wave_sum_bcast(float x) {
    x = dpp_add<0x111, 0xf, true >(x);  // row_shr:1
    x = dpp_add<0x112, 0xf, true >(x);  // row_shr:2
    x = dpp_add<0x114, 0xf, true >(x);  // row_shr:4
    x = dpp_add<0x118, 0xf, true >(x);  // row_shr:8
    x = dpp_add<0x142, 0xa, false>(x);  // row_bcast:15
    x = dpp_add<0x143, 0xc, false>(x);  // row_bcast:31
    return __int_as_float(__builtin_amdgcn_readlane(__float_as_int(x), 63));
}

// K1: ragged-prefix mean pool over word embeddings + doc_feat accumulation.
// EXACT R13 form (proven ~76us aux config): 128 threads, scalar coalesced
// loads, compiler-scheduled gather. (R19's hand-vectorized 64-thread variant
// regressed aux 76 -> 122us — structural-rewrite ledger entry #5.)
__global__ __launch_bounds__(128) void k_sent(const int* __restrict__ x,
                                              const float* __restrict__ word_emb,
                                              float* __restrict__ sent,
                                              float* __restrict__ doc_sum) {
    __shared__ int toks[W];
    __shared__ int s_len;
    const int i = blockIdx.x, t = threadIdx.x;
    if (t == 0) s_len = 0;
    __syncthreads();
    if (t < W) {
        int tok = x[i * W + t];
        toks[t] = tok;
        if (tok > 0) atomicAdd(&s_len, 1);
    }
    __syncthreads();
    const int len = s_len;
    if (t < E) {
        float acc = 0.0f;
        for (int j = 0; j < len; ++j)
            acc += word_emb[toks[j] * E + t];   // coalesced across t
        float val = acc / (float)max(len, 1);
        sent[i * E + t] = val;
        atomicAdd(&doc_sum[t], val * (1.0f / (float)S));
    }
}

// K2: doc = tanh(doc_feat @ fc1_w.T + fc1_b); cvec = Wc + Ws @ doc
__global__ __launch_bounds__(128) void k_doc(const float* __restrict__ doc_sum,
                                             const float* __restrict__ fc1_w,
                                             const float* __restrict__ fc1_b,
                                             const float* __restrict__ Wc,
                                             const float* __restrict__ Ws,
                                             float* __restrict__ cvec) {
    __shared__ float s_df[E];
    __shared__ float s_doc[H];
    const int t = threadIdx.x;
    if (t < E) s_df[t] = doc_sum[t];
    __syncthreads();
    if (t < H) {
        float acc = fc1_b[t];
        for (int k = 0; k < E; ++k) acc += s_df[k] * fc1_w[t * E + k];
        s_doc[t] = tanhf(acc);
    }
    __syncthreads();
    if (t < H) {
        float c = Wc[t];
        for (int j = 0; j < H; ++j) c += Ws[t * H + j] * s_doc[j];
        cvec[t] = c;
    }
}

// K3: per-row padded layout for the scan (R12/R13 layout).
// packed row i = 64 float4 slots; slot m = (L2E*hWr[2m], h[2m], L2E*hWr[2m+1], h[2m+1]),
// zeros for k>=100.  Slot 50 .x (element 200, a DEAD hWr position) carries
// q[i] = -L2E*(h.cvec + pos.Wp + b); the scan keeps lane 50's t0 = 1 so
// part(lane50) = t0*q injects q into the wave sum for free.
// Grid is S+16: pad blocks (i >= S) zero-fill their row for the scan's
// prefetch overrun (replaces the separate memset launch).
__global__ __launch_bounds__(128) void k_row(const float* __restrict__ sent,
                                             const float* __restrict__ fc2_w,
                                             const float* __restrict__ fc2_b,
                                             const float* __restrict__ Wr,
                                             const float* __restrict__ cvec,
                                             const float* __restrict__ pos_emb,
                                             const float* __restrict__ Wp,
                                             const float* __restrict__ bptr,
                                             float* __restrict__ packed) {
    __shared__ float s_sent[E];
    __shared__ float s_h[H];
    __shared__ float red[128];
    const int i = blockIdx.x, t = threadIdx.x;
    float* row = packed + (size_t)i * 256;
    if (i >= S) {                       // zero-fill pad rows
        row[2 * t] = 0.0f;
        row[2 * t + 1] = 0.0f;
        return;
    }
    if (t < E) s_sent[t] = sent[i * E + t];
    __syncthreads();
    float hv = 0.0f;
    if (t < H) {
        float acc = fc2_b[t];
        for (int k = 0; k < E; ++k) acc += s_sent[k] * fc2_w[t * E + k];
        hv = tanhf(acc);
        s_h[t] = hv;
    }
    __syncthreads();
    {
        const int m = t >> 1, o = (t & 1) * 2;
        if (t < H) {
            float acc = 0.0f;
            for (int k = 0; k < H; ++k) acc += s_h[k] * Wr[k * H + t];   // coalesced across t
            row[m * 4 + o]     = 1.44269504f * acc;  // L2E * hWr
            row[m * 4 + o + 1] = hv;                 // h
        } else {
            if (t != 100) row[m * 4 + o] = 0.0f;   // dead w (element 200 reserved for q)
            row[m * 4 + o + 1] = 0.0f;             // dead h
        }
    }
    float p = 0.0f;
    if (t < H) p = hv * cvec[t];
    if (t < PD) p += pos_emb[i * PD + t] * Wp[t];
    red[t] = p;
    __syncthreads();
    for (int m = 64; m > 0; m >>= 1) {
        if (t < m) red[t] += red[t + m];
        __syncthreads();
    }
    if (t == 0) row[200] = -1.44269504f * (red[0] + bptr[0]);  // slot 50 .x
}

// K4: sequential scan — the R12-submitted kernel (best measured: 240us).
// Batch-8 double-buffered manual pipeline, pinned schedule, ONE rcp on the
// recurrence chain:
//   a = 1 + 2^total  (prob = 1/a off-chain, output only)
//   tanh-addition scaled by a^3: inner = h*a^2 - h^3/3 (h^3/3 off-chain)
//   N = t*a^3 + inner;  D = a^3 + t*inner;  t' = N * rcp(D)
// Lane 50: t0 = 1 forever (its h = 0), injecting q = row[200] for free.
// Structural ledger (R10/R14/R15/R16/R18/R19): every deviation from this
// structure regressed; only algebra-depth cuts (R12, R13) won.
__global__ __launch_bounds__(64, 1) void k_scan(const f32x4* __restrict__ packed,
                                                float* __restrict__ out) {
    const int l = threadIdx.x;
    const f32x4* pf = packed + l;

    float t0 = (l == 50) ? 1.0f : 0.0f;   // t = tanh(s); lane50 carries q
    float t1 = 0.0f, probbuf = 0.0f;

    f32x4 x0, x1, x2, x3, x4, x5, x6, x7;
    f32x4 y0, y1, y2, y3, y4, y5, y6, y7;

#define SB() __builtin_amdgcn_sched_barrier(0)
#define ISSUE(AR, PTR) \
    asm volatile("global_load_dwordx4 %0, %1, off" : "=v"(AR) : "v"(PTR))
#define ISSUE8(P0, P1, P2, P3, P4, P5, P6, P7)                                \
    SB();                                                                     \
    ISSUE(P0, pf + 0 * 64); ISSUE(P1, pf + 1 * 64);                           \
    ISSUE(P2, pf + 2 * 64); ISSUE(P3, pf + 3 * 64);                           \
    ISSUE(P4, pf + 4 * 64); ISSUE(P5, pf + 5 * 64);                           \
    ISSUE(P6, pf + 6 * 64); ISSUE(P7, pf + 7 * 64);                           \
    pf += 8 * 64;                                                             \
    SB();
#define WAIT_ALL()                                                            \
    SB();                                                                     \
    asm volatile("s_waitcnt vmcnt(0)" ::: "memory");                          \
    SB();

#define STEP(CA_, IDX, G)                                                     \
    {                                                                         \
        /* off-chain: h^3/3 (from loaded data, lands a full batch early) */   \
        float h30 = CA_.y * CA_.y * CA_.y * 0.33333334f;                      \
        float h31 = CA_.w * CA_.w * CA_.w * 0.33333334f;                      \
        float part = fmaf(t0, CA_.x, t1 * CA_.z);                             \
        float total = wave_sum_bcast(part);  /* = L2E*(hWr.tanh(s) - pre) */  \
        float e2 = exp2f(total);                                              \
        float a  = e2 + 1.0f;                                                 \
        float a2 = a * a;                                                     \
        float a3 = a2 * a;                                                    \
        float in0 = fmaf(CA_.y, a2, -h30);                                    \
        float in1 = fmaf(CA_.w, a2, -h31);                                    \
        float N0 = fmaf(t0, a3, in0), D0 = fmaf(t0, in0, a3);                 \
        float N1 = fmaf(t1, a3, in1), D1 = fmaf(t1, in1, a3);                 \
        t0 = N0 * fast_rcp(D0);                                               \
        t1 = N1 * fast_rcp(D1);                                               \
        float prob = fast_rcp(a);            /* off the recurrence chain */   \
        probbuf = (l == ((G + IDX) & 63)) ? prob : probbuf;                   \
    }
#define COMPUTE8(P0, P1, P2, P3, P4, P5, P6, P7, G)                           \
    STEP(P0, 0, G) STEP(P1, 1, G) STEP(P2, 2, G) STEP(P3, 3, G)               \
    STEP(P4, 4, G) STEP(P5, 5, G) STEP(P6, 6, G) STEP(P7, 7, G)               \
    if (((G) & 63) == 56) out[((G) & ~63) + l] = probbuf;

    // Preload batch 0 into X and land it.
    ISSUE8(x0, x1, x2, x3, x4, x5, x6, x7)
    WAIT_ALL()

    for (int base = 0; base < S; base += 16) {
        ISSUE8(y0, y1, y2, y3, y4, y5, y6, y7)            // rows base+8..base+15
        COMPUTE8(x0, x1, x2, x3, x4, x5, x6, x7, base)    // rows base..base+7
        WAIT_ALL()                                        // Y landed (issued ~1500cy ago)
        ISSUE8(x0, x1, x2, x3, x4, x5, x6, x7)            // rows base+16..base+23
        COMPUTE8(y0, y1, y2, y3, y4, y5, y6, y7, base + 8)
        WAIT_ALL()                                        // X landed
    }
#undef COMPUTE8
#undef STEP
#undef WAIT_ALL
#undef ISSUE8
#undef ISSUE
#undef SB
}

extern "C" void kernel_launch(void* const* d_in, const int* in_sizes, int n_in,
                              void* d_out, int out_size, void* d_ws, size_t ws_size,
                              hipStream_t stream) {
    const int*   x        = (const int*)  d_in[0];
    const float* word_emb = (const float*)d_in[1];
    const float* pos_emb  = (const float*)d_in[2];
    const float* fc1_w    = (const float*)d_in[3];
    const float* fc1_b    = (const float*)d_in[4];
    const float* fc2_w    = (const float*)d_in[5];
    const float* fc2_b    = (const float*)d_in[6];
    const float* Wc       = (const float*)d_in[7];
    const float* Ws       = (const float*)d_in[8];
    const float* Wr       = (const float*)d_in[9];
    const float* Wp       = (const float*)d_in[10];
    const float* bptr     = (const float*)d_in[11];
    float* out = (float*)d_out;

    float* wsf      = (float*)d_ws;
    float* doc_sum  = wsf;                 // 128 (zeroed each call)
    float* cvec     = wsf + 128;           // 128
    float* sent     = wsf + 256;           // S*E = 204800
    float* packed   = sent + S * E;        // (S+16)*256 floats, 16B-aligned offset

    hipMemsetAsync(doc_sum, 0, E * sizeof(float), stream);
    k_sent<<<S, 128, 0, stream>>>(x, word_emb, sent, doc_sum);
    k_doc<<<1, 128, 0, stream>>>(doc_sum, fc1_w, fc1_b, Wc, Ws, cvec);
    k_row<<<S + 16, 128, 0, stream>>>(sent, fc2_w, fc2_b, Wr, cvec, pos_emb, Wp, bptr, packed);
    k_scan<<<1, 64, 0, stream>>>((const f32x4*)packed, out);
}